// Round 3
// baseline (301.385 us; speedup 1.0000x reference)
//
#include <hip/hip_runtime.h>
#include <float.h>
#include <limits.h>
#include <stdint.h>

constexpr int N = 16384;
constexpr int K = 8192;
constexpr int D = 256;

typedef _Float16 half8_t __attribute__((ext_vector_type(8)));
typedef float float4_t __attribute__((ext_vector_type(4)));

// ---------------- fallback helper: row sum-of-squares (one wave per row) ----
__global__ void vq_rowsq(const float* __restrict__ A, float* __restrict__ out) {
    int row = blockIdx.x;
    int lane = threadIdx.x;  // 64
    float4 v = ((const float4*)(A + (size_t)row * D))[lane];
    float s = v.x * v.x + v.y * v.y + v.z * v.z + v.w * v.w;
    #pragma unroll
    for (int o = 32; o > 0; o >>= 1) s += __shfl_down(s, o);
    if (lane == 0) out[row] = s;
}

// =======================================================================
// FAST PATH: f16 split-2 MFMA GEMM + fused top-2 argmin + fp32 rescore
// =======================================================================

// Combined pre-tile+split for X and E, plus fused esq (E row sum-of-squares).
// chunk = 8 dims (16B). region(rt,ds) = 128 rows x 4 quads = 512 chunks at
// slot = lr*4 + (quad ^ ((lr>>1)&3)): ds_read_b128 fragment reads land 2-way
// max on banks AND global_load_lds staging is lane-linear.
__global__ void vq_prep(const float* __restrict__ X, const float* __restrict__ E,
                        _Float16* __restrict__ Xh, _Float16* __restrict__ Xl,
                        _Float16* __restrict__ Eh, _Float16* __restrict__ El,
                        float* __restrict__ esq) {
    int c = blockIdx.x * 256 + threadIdx.x;
    const int XCH = N * 32;  // X chunk count (blocks are all-X or all-E: XCH % 256 == 0)
    bool isX = c < XCH;
    const float* src;
    _Float16 *h, *l;
    int cc;
    if (isX) { src = X; h = Xh; l = Xl; cc = c; }
    else     { src = E; h = Eh; l = El; cc = c - XCH; }
    int r = cc >> 5;         // source row
    int q8 = cc & 31;        // 8-dim chunk within row
    int ds = q8 >> 2, quad = q8 & 3;
    int rt = r >> 7, lr = r & 127;
    int slot = lr * 4 + (quad ^ ((lr >> 1) & 3));
    size_t dst = ((size_t)(rt * 8 + ds) * 512 + (size_t)slot) * 8;
    const float4* s4 = (const float4*)(src + (size_t)r * D + q8 * 8);
    float4 v0 = s4[0], v1 = s4[1];
    float x[8] = {v0.x, v0.y, v0.z, v0.w, v1.x, v1.y, v1.z, v1.w};
    half8_t hh, ll;
    float sq = 0.f;
    #pragma unroll
    for (int i = 0; i < 8; i++) {
        _Float16 hi = (_Float16)x[i];
        hh[i] = hi;
        ll[i] = (_Float16)(x[i] - (float)hi);  // x - hi exact in fp32
        sq += x[i] * x[i];
    }
    *(half8_t*)(h + dst) = hh;
    *(half8_t*)(l + dst) = ll;
    if (!isX) {
        // 32 consecutive lanes share a row; xor-reduce within the 32-group
        #pragma unroll
        for (int o = 16; o > 0; o >>= 1) sq += __shfl_xor(sq, o);
        if ((threadIdx.x & 31) == 0) esq[r] = sq;
    }
}

__device__ __forceinline__ void ldg_lds16(const _Float16* g, _Float16* l) {
    __builtin_amdgcn_global_load_lds(
        (const __attribute__((address_space(1))) unsigned int*)g,
        (__attribute__((address_space(3))) unsigned int*)l, 16, 0, 0);
}

constexpr int CS = 8;  // K-split: 1024 blocks -> 3-4 resident blocks/CU
constexpr int KT = K / 128 / CS;  // code tiles per block = 8

// block: 256 thr = 4 waves, tile 128 rows x 128 codes, waves 2x2 (64x64 each)
// LDS: [Xh|Xl|Eh|El] regions of 8KB per 32-dim step, single-buffered.
__global__ __launch_bounds__(256, 2) void vq_mfma(
    const _Float16* __restrict__ Xh, const _Float16* __restrict__ Xl,
    const _Float16* __restrict__ Eh, const _Float16* __restrict__ El,
    const float* __restrict__ esq, uint32_t* __restrict__ pcand) {
    __shared__ _Float16 lds[16384];  // 32KB

    const int t = threadIdx.x, w = t >> 6, lane = t & 63;
    const int rt = blockIdx.x;  // row tile 0..127
    const int cs = blockIdx.y;  // code split 0..7
    const int r15 = lane & 15, quad = lane >> 4;
    const int sw = quad ^ ((r15 >> 1) & 3);
    const int abase = ((w >> 1) * 64 + r15) * 4 + sw;
    const int bbase = ((w & 1) * 64 + r15) * 4 + sw;

    float best[16];
    int bidx[16];
    #pragma unroll
    for (int i = 0; i < 16; i++) { best[i] = FLT_MAX; bidx[i] = 0; }

    const half8_t* Xh_l = (const half8_t*)lds;
    const half8_t* Xl_l = (const half8_t*)(lds + 4096);
    const half8_t* Eh_l = (const half8_t*)(lds + 8192);
    const half8_t* El_l = (const half8_t*)(lds + 12288);

    for (int kt2 = 0; kt2 < KT; kt2++) {
        const int ct = cs * KT + kt2;   // global code tile 0..63
        const int code0 = ct * 128;

        float4_t acc[4][4];
        #pragma unroll
        for (int mt = 0; mt < 4; mt++)
            #pragma unroll
            for (int nt = 0; nt < 4; nt++) acc[mt][nt] = {0.f, 0.f, 0.f, 0.f};

        for (int ds = 0; ds < 8; ds++) {
            __syncthreads();
            {  // wave w stages region w (8 x 1KB lane-linear chunks)
                size_t xoff = ((size_t)rt * 8 + ds) * 4096;
                size_t eoff = ((size_t)ct * 8 + ds) * 4096;
                const _Float16* s = (w == 0) ? Xh + xoff
                                  : (w == 1) ? Xl + xoff
                                  : (w == 2) ? Eh + eoff
                                             : El + eoff;
                _Float16* d = lds + w * 4096;
                #pragma unroll
                for (int i = 0; i < 8; i++)
                    ldg_lds16(s + (size_t)(i * 64 + lane) * 8, d + i * 512);
            }
            __syncthreads();

            half8_t Ah[4], Al[4], Bh[4], Bl[4];
            #pragma unroll
            for (int mt = 0; mt < 4; mt++) {
                Ah[mt] = Xh_l[abase + mt * 64];
                Al[mt] = Xl_l[abase + mt * 64];
            }
            #pragma unroll
            for (int nt = 0; nt < 4; nt++) {
                Bh[nt] = Eh_l[bbase + nt * 64];
                Bl[nt] = El_l[bbase + nt * 64];
            }
            #pragma unroll
            for (int mt = 0; mt < 4; mt++)
                #pragma unroll
                for (int nt = 0; nt < 4; nt++) {
                    acc[mt][nt] = __builtin_amdgcn_mfma_f32_16x16x32_f16(
                        Ah[mt], Bh[nt], acc[mt][nt], 0, 0, 0);
                    acc[mt][nt] = __builtin_amdgcn_mfma_f32_16x16x32_f16(
                        Ah[mt], Bl[nt], acc[mt][nt], 0, 0, 0);
                    acc[mt][nt] = __builtin_amdgcn_mfma_f32_16x16x32_f16(
                        Al[mt], Bh[nt], acc[mt][nt], 0, 0, 0);
                }
        }

        // epilogue: s = esq[code] - 2*dot  (x_sq is argmin-invariant)
        #pragma unroll
        for (int nt = 0; nt < 4; nt++) {
            const int code = code0 + (w & 1) * 64 + nt * 16 + r15;
            const float eq = esq[code];
            #pragma unroll
            for (int mt = 0; mt < 4; mt++)
                #pragma unroll
                for (int rg = 0; rg < 4; rg++) {
                    float s = fmaf(-2.f, acc[mt][nt][rg], eq);
                    int sl = mt * 4 + rg;
                    if (s < best[sl]) { best[sl] = s; bidx[sl] = code; }
                }
        }
    }

    // block reduction: per row, top-2 over 32 contributors; pack 13+13 bits
    __syncthreads();
    float* smin = (float*)lds;           // [32][128]
    int* sidx = (int*)(lds + 8192);      // [32][128]
    const int cont = (w & 1) * 16 + r15;
    #pragma unroll
    for (int sl = 0; sl < 16; sl++) {
        int row = (w >> 1) * 64 + (sl >> 2) * 16 + quad * 4 + (sl & 3);
        smin[cont * 128 + row] = best[sl];
        sidx[cont * 128 + row] = bidx[sl];
    }
    __syncthreads();
    if (t < 128) {
        float m1 = FLT_MAX, m2 = FLT_MAX;
        int i1 = 0, i2 = 0;
        for (int c = 0; c < 32; c++) {
            float v = smin[c * 128 + t];
            int id = sidx[c * 128 + t];
            if (v < m1 || (v == m1 && id < i1)) {
                m2 = m1; i2 = i1; m1 = v; i1 = id;
            } else if (v < m2 || (v == m2 && id < i2)) {
                m2 = v; i2 = id;
            }
        }
        uint32_t u = ((uint32_t)i1 << 13) | (uint32_t)(i2 & 8191);
        pcand[(size_t)(rt * 128 + t) * CS + cs] = u;
    }
}

__device__ __forceinline__ float wave_sum(float v) {
    #pragma unroll
    for (int o = 1; o < 64; o <<= 1) v += __shfl_xor(v, o);
    return v;
}

// rescore all 16 candidates in exact fp32 (reference formula/order), gather.
__global__ void vq_rescore(const float* __restrict__ X, const float* __restrict__ E,
                           const uint32_t* __restrict__ pcand, float* __restrict__ out_q,
                           float* __restrict__ out_idx) {
    int row = blockIdx.x * 4 + (threadIdx.x >> 6);
    int lane = threadIdx.x & 63;
    float4 xv = ((const float4*)(X + (size_t)row * D))[lane];
    float xs = wave_sum(xv.x * xv.x + xv.y * xv.y + xv.z * xv.z + xv.w * xv.w);

    int idx[2 * CS];
    #pragma unroll
    for (int s = 0; s < CS; s++) {
        uint32_t u = pcand[(size_t)row * CS + s];
        idx[2 * s] = (int)(u >> 13);
        idx[2 * s + 1] = (int)(u & 8191);
    }
    // hoist all candidate-row gathers for memory-level parallelism
    float4 ev[2 * CS];
    #pragma unroll
    for (int c = 0; c < 2 * CS; c++)
        ev[c] = ((const float4*)(E + (size_t)idx[c] * D))[lane];

    float bestv = FLT_MAX;
    int besti = INT_MAX;
    #pragma unroll
    for (int c = 0; c < 2 * CS; c++) {
        float4 e = ev[c];
        float dp = wave_sum(xv.x * e.x + xv.y * e.y + xv.z * e.z + xv.w * e.w);
        float eq = wave_sum(e.x * e.x + e.y * e.y + e.z * e.z + e.w * e.w);
        float s = (xs + eq) - 2.f * dp;
        int id = idx[c];
        if (s < bestv || (s == bestv && id < besti)) { bestv = s; besti = id; }
    }
    if (lane == 0) out_idx[row] = (float)besti;
    float4 bv = ((const float4*)(E + (size_t)besti * D))[lane];
    ((float4*)(out_q + (size_t)row * D))[lane] = bv;
}

// =======================================================================
// FALLBACK (proven R1 fp32 path) — used only if ws_size is too small
// =======================================================================
constexpr int BM = 128, BN = 128, DK = 32, KSPLIT = 8;
constexpr int KCHUNK = K / KSPLIT;
constexpr int LDX = BM + 4, LDE = BN + 4;

__global__ __launch_bounds__(256) void vq_main(
    const float* __restrict__ X, const float* __restrict__ E,
    const float* __restrict__ xsq, const float* __restrict__ esq,
    float* __restrict__ pmin, int* __restrict__ pidx) {
    __shared__ float sx[DK * LDX];
    __shared__ float se[DK * LDE];
    const int t = threadIdx.x;
    const int row0 = blockIdx.x * BM;
    const int kbeg = blockIdx.y * KCHUNK;
    const int lane = t & 63, wave = t >> 6;
    const int lm = lane >> 3, ln = lane & 7;
    const int mf = (wave >> 1) * 64 + lm * 8;
    const int nf = (wave & 1) * 64 + ln * 8;
    float xs[8];
    #pragma unroll
    for (int i = 0; i < 8; i++) xs[i] = xsq[row0 + mf + i];
    float rmin[8];
    int ridx[8];
    #pragma unroll
    for (int i = 0; i < 8; i++) { rmin[i] = FLT_MAX; ridx[i] = 0; }
    const int sm = t >> 3;
    const int sd = (t & 7) * 4;
    for (int kt = kbeg; kt < kbeg + KCHUNK; kt += BN) {
        float acc[8][8];
        #pragma unroll
        for (int i = 0; i < 8; i++)
            #pragma unroll
            for (int j = 0; j < 8; j++) acc[i][j] = 0.0f;
        for (int d0 = 0; d0 < D; d0 += DK) {
            __syncthreads();
            #pragma unroll
            for (int r = 0; r < 4; r++) {
                int row = sm + 32 * r;
                float4 v = *(const float4*)(X + (size_t)(row0 + row) * D + d0 + sd);
                sx[(sd + 0) * LDX + row] = v.x;
                sx[(sd + 1) * LDX + row] = v.y;
                sx[(sd + 2) * LDX + row] = v.z;
                sx[(sd + 3) * LDX + row] = v.w;
                float4 ww = *(const float4*)(E + (size_t)(kt + row) * D + d0 + sd);
                se[(sd + 0) * LDE + row] = ww.x;
                se[(sd + 1) * LDE + row] = ww.y;
                se[(sd + 2) * LDE + row] = ww.z;
                se[(sd + 3) * LDE + row] = ww.w;
            }
            __syncthreads();
            #pragma unroll
            for (int d = 0; d < DK; d++) {
                float4 a0 = *(const float4*)(sx + d * LDX + mf);
                float4 a1 = *(const float4*)(sx + d * LDX + mf + 4);
                float4 b0 = *(const float4*)(se + d * LDE + nf);
                float4 b1 = *(const float4*)(se + d * LDE + nf + 4);
                float a[8] = {a0.x, a0.y, a0.z, a0.w, a1.x, a1.y, a1.z, a1.w};
                float b[8] = {b0.x, b0.y, b0.z, b0.w, b1.x, b1.y, b1.z, b1.w};
                #pragma unroll
                for (int i = 0; i < 8; i++)
                    #pragma unroll
                    for (int j = 0; j < 8; j++) acc[i][j] += a[i] * b[j];
            }
        }
        float es[8];
        #pragma unroll
        for (int j = 0; j < 8; j++) es[j] = esq[kt + nf + j];
        #pragma unroll
        for (int i = 0; i < 8; i++)
            #pragma unroll
            for (int j = 0; j < 8; j++) {
                float s = (xs[i] + es[j]) - 2.0f * acc[i][j];
                if (s < rmin[i]) { rmin[i] = s; ridx[i] = kt + nf + j; }
            }
    }
    __syncthreads();
    float* redm = sx;
    int* redi = (int*)se;
    const int c = (wave & 1) * 8 + ln;
    #pragma unroll
    for (int i = 0; i < 8; i++) {
        int r = (wave >> 1) * 64 + lm * 8 + i;
        redm[r * 16 + c] = rmin[i];
        redi[r * 16 + c] = ridx[i];
    }
    __syncthreads();
    if (t < BM) {
        float bst = redm[t * 16];
        int bi = redi[t * 16];
        #pragma unroll
        for (int c2 = 1; c2 < 16; c2++) {
            float v = redm[t * 16 + c2];
            int id = redi[t * 16 + c2];
            if (v < bst || (v == bst && id < bi)) { bst = v; bi = id; }
        }
        pmin[(size_t)(row0 + t) * KSPLIT + blockIdx.y] = bst;
        pidx[(size_t)(row0 + t) * KSPLIT + blockIdx.y] = bi;
    }
}

__global__ void vq_final(const float* __restrict__ E, const float* __restrict__ pmin,
                         const int* __restrict__ pidx, float* __restrict__ out_q,
                         float* __restrict__ out_idx) {
    int row = blockIdx.x;
    int lane = threadIdx.x;
    float bst = pmin[(size_t)row * KSPLIT];
    int bi = pidx[(size_t)row * KSPLIT];
    #pragma unroll
    for (int s = 1; s < KSPLIT; s++) {
        float v = pmin[(size_t)row * KSPLIT + s];
        int id = pidx[(size_t)row * KSPLIT + s];
        if (v < bst || (v == bst && id < bi)) { bst = v; bi = id; }
    }
    if (lane == 0) out_idx[row] = (float)bi;
    float4 v = ((const float4*)(E + (size_t)bi * D))[lane];
    ((float4*)(out_q + (size_t)row * D))[lane] = v;
}

// =======================================================================
extern "C" void kernel_launch(void* const* d_in, const int* in_sizes, int n_in,
                              void* d_out, int out_size, void* d_ws, size_t ws_size,
                              hipStream_t stream) {
    const float* X = (const float*)d_in[0];  // [N, D]
    const float* E = (const float*)d_in[1];  // [K, D]
    float* out_q = (float*)d_out;
    float* out_idx = (float*)d_out + (size_t)N * D;

    // fast-path ws layout: Xh(8M) Xl(8M) Eh(4M) El(4M) esq(32K) pcand(N*CS*4 = 512K)
    const size_t need = (size_t)24 * 1024 * 1024 + 32768 + (size_t)N * CS * 4;
    if (ws_size >= need) {
        _Float16* Xh = (_Float16*)d_ws;
        _Float16* Xl = Xh + (size_t)N * D;
        _Float16* Eh = Xl + (size_t)N * D;
        _Float16* El = Eh + (size_t)K * D;
        float* esq = (float*)(El + (size_t)K * D);
        uint32_t* pcand = (uint32_t*)(esq + K);

        vq_prep<<<(N + K) * 32 / 256, 256, 0, stream>>>(X, E, Xh, Xl, Eh, El, esq);
        dim3 grid(N / 128, CS);
        vq_mfma<<<grid, 256, 0, stream>>>(Xh, Xl, Eh, El, esq, pcand);
        vq_rescore<<<N / 4, 256, 0, stream>>>(X, E, pcand, out_q, out_idx);
    } else {
        float* esq = (float*)d_ws;
        float* xsq = esq + K;
        float* pmin = xsq + N;
        int* pidx = (int*)(pmin + (size_t)N * KSPLIT);
        vq_rowsq<<<K, 64, 0, stream>>>(E, esq);
        vq_rowsq<<<N, 64, 0, stream>>>(X, xsq);
        dim3 grid(N / BM, KSPLIT);
        vq_main<<<grid, 256, 0, stream>>>(X, E, xsq, esq, pmin, pidx);
        vq_final<<<N, 64, 0, stream>>>(E, pmin, pidx, out_q, out_idx);
    }
}

// Round 4
// 268.455 us; speedup vs baseline: 1.1227x; 1.1227x over previous
//
#include <hip/hip_runtime.h>
#include <float.h>
#include <limits.h>
#include <stdint.h>

constexpr int N = 16384;
constexpr int K = 8192;
constexpr int D = 256;

typedef _Float16 half8_t __attribute__((ext_vector_type(8)));
typedef float float4_t __attribute__((ext_vector_type(4)));

// ---------------- fallback helper: row sum-of-squares (one wave per row) ----
__global__ void vq_rowsq(const float* __restrict__ A, float* __restrict__ out) {
    int row = blockIdx.x;
    int lane = threadIdx.x;  // 64
    float4 v = ((const float4*)(A + (size_t)row * D))[lane];
    float s = v.x * v.x + v.y * v.y + v.z * v.z + v.w * v.w;
    #pragma unroll
    for (int o = 32; o > 0; o >>= 1) s += __shfl_down(s, o);
    if (lane == 0) out[row] = s;
}

// =======================================================================
// FAST PATH: f16 split-2 MFMA GEMM + fused top-2 argmin + margin-gated rescore
// =======================================================================

// Combined pre-tile+split for X and E, plus fused esq (E row sum-of-squares).
// chunk = 8 dims (16B). region(rt,ds) = 128 rows x 4 quads = 512 chunks at
// slot = lr*4 + (quad ^ ((lr>>1)&3)): ds_read_b128 fragment reads land 2-way
// max on banks AND global_load_lds staging is lane-linear.
__global__ void vq_prep(const float* __restrict__ X, const float* __restrict__ E,
                        _Float16* __restrict__ Xh, _Float16* __restrict__ Xl,
                        _Float16* __restrict__ Eh, _Float16* __restrict__ El,
                        float* __restrict__ esq) {
    int c = blockIdx.x * 256 + threadIdx.x;
    const int XCH = N * 32;  // X chunk count (XCH % 256 == 0: blocks all-X or all-E)
    bool isX = c < XCH;
    const float* src;
    _Float16 *h, *l;
    int cc;
    if (isX) { src = X; h = Xh; l = Xl; cc = c; }
    else     { src = E; h = Eh; l = El; cc = c - XCH; }
    int r = cc >> 5;         // source row
    int q8 = cc & 31;        // 8-dim chunk within row
    int ds = q8 >> 2, quad = q8 & 3;
    int rt = r >> 7, lr = r & 127;
    int slot = lr * 4 + (quad ^ ((lr >> 1) & 3));
    size_t dst = ((size_t)(rt * 8 + ds) * 512 + (size_t)slot) * 8;
    const float4* s4 = (const float4*)(src + (size_t)r * D + q8 * 8);
    float4 v0 = s4[0], v1 = s4[1];
    float x[8] = {v0.x, v0.y, v0.z, v0.w, v1.x, v1.y, v1.z, v1.w};
    half8_t hh, ll;
    float sq = 0.f;
    #pragma unroll
    for (int i = 0; i < 8; i++) {
        _Float16 hi = (_Float16)x[i];
        hh[i] = hi;
        ll[i] = (_Float16)(x[i] - (float)hi);  // x - hi exact in fp32
        sq += x[i] * x[i];
    }
    *(half8_t*)(h + dst) = hh;
    *(half8_t*)(l + dst) = ll;
    if (!isX) {
        // 32 consecutive lanes share a row; xor-reduce within the 32-group
        #pragma unroll
        for (int o = 16; o > 0; o >>= 1) sq += __shfl_xor(sq, o);
        if ((threadIdx.x & 31) == 0) esq[r] = sq;
    }
}

__device__ __forceinline__ void ldg_lds16(const _Float16* g, _Float16* l) {
    __builtin_amdgcn_global_load_lds(
        (const __attribute__((address_space(1))) unsigned int*)g,
        (__attribute__((address_space(3))) unsigned int*)l, 16, 0, 0);
}

constexpr int CS = 4;            // K-split: grid 512 = exactly 2 blocks/CU
constexpr int KT = K / 128 / CS; // 16 code tiles per block
constexpr int NSTEP = KT * 8;    // flattened (ctile, ds) steps

// block: 256 thr = 4 waves, tile 128 rows x 128 codes, waves 2x2 (64x64 each)
// LDS: DOUBLE-buffered [Xh|Xl|Eh|El] regions (8KB each) = 64KB total.
// Pipeline: barrier -> issue stage(s+1) -> ds_read+MFMA(s). The vmcnt(0)
// drain at each barrier waits on loads issued a full compute-step earlier.
__global__ __launch_bounds__(256, 2) void vq_mfma(
    const _Float16* __restrict__ Xh, const _Float16* __restrict__ Xl,
    const _Float16* __restrict__ Eh, const _Float16* __restrict__ El,
    const float* __restrict__ esq, float4* __restrict__ pcand) {
    __shared__ _Float16 lds[32768];  // 64KB = 2 bufs x 4 regions x 4096 halves

    const int t = threadIdx.x, w = t >> 6, lane = t & 63;
    const int rt = blockIdx.x;  // row tile 0..127
    const int cs = blockIdx.y;  // code split 0..3
    const int r15 = lane & 15, quad = lane >> 4;
    const int sw = quad ^ ((r15 >> 1) & 3);
    const int abase = ((w >> 1) * 64 + r15) * 4 + sw;  // chunk-slot (16B units)
    const int bbase = ((w & 1) * 64 + r15) * 4 + sw;

    float best[16];
    int bidx[16];
    #pragma unroll
    for (int i = 0; i < 16; i++) { best[i] = FLT_MAX; bidx[i] = 0; }

    // wave w stages region w of buf[(s)&1] for step s
    auto stage = [&](int s) {
        const int ct = cs * KT + (s >> 3), ds = s & 7;
        size_t xoff = ((size_t)rt * 8 + ds) * 4096;
        size_t eoff = ((size_t)ct * 8 + ds) * 4096;
        const _Float16* src = (w == 0) ? Xh + xoff
                            : (w == 1) ? Xl + xoff
                            : (w == 2) ? Eh + eoff
                                       : El + eoff;
        _Float16* dst = lds + (s & 1) * 16384 + w * 4096;
        #pragma unroll
        for (int i = 0; i < 8; i++)
            ldg_lds16(src + (size_t)(i * 64 + lane) * 8, dst + i * 512);
    };

    stage(0);

    float4_t acc[4][4];
    #pragma unroll
    for (int mt = 0; mt < 4; mt++)
        #pragma unroll
        for (int nt = 0; nt < 4; nt++) acc[mt][nt] = {0.f, 0.f, 0.f, 0.f};

    for (int s = 0; s < NSTEP; s++) {
        __syncthreads();  // drains stage(s) (issued one full step ago, except s=0)
        if (s + 1 < NSTEP) stage(s + 1);

        const _Float16* buf = lds + (s & 1) * 16384;
        const half8_t* Xh_l = (const half8_t*)buf;
        const half8_t* Xl_l = (const half8_t*)(buf + 4096);
        const half8_t* Eh_l = (const half8_t*)(buf + 8192);
        const half8_t* El_l = (const half8_t*)(buf + 12288);

        half8_t Ah[4], Al[4], Bh[4], Bl[4];
        #pragma unroll
        for (int mt = 0; mt < 4; mt++) {
            Ah[mt] = Xh_l[abase + mt * 64];
            Al[mt] = Xl_l[abase + mt * 64];
        }
        #pragma unroll
        for (int nt = 0; nt < 4; nt++) {
            Bh[nt] = Eh_l[bbase + nt * 64];
            Bl[nt] = El_l[bbase + nt * 64];
        }
        #pragma unroll
        for (int mt = 0; mt < 4; mt++)
            #pragma unroll
            for (int nt = 0; nt < 4; nt++) {
                acc[mt][nt] = __builtin_amdgcn_mfma_f32_16x16x32_f16(
                    Ah[mt], Bh[nt], acc[mt][nt], 0, 0, 0);
                acc[mt][nt] = __builtin_amdgcn_mfma_f32_16x16x32_f16(
                    Ah[mt], Bl[nt], acc[mt][nt], 0, 0, 0);
                acc[mt][nt] = __builtin_amdgcn_mfma_f32_16x16x32_f16(
                    Al[mt], Bh[nt], acc[mt][nt], 0, 0, 0);
            }

        if ((s & 7) == 7) {  // ctile finished: epilogue + acc reset
            const int code0 = (cs * KT + (s >> 3)) * 128;
            #pragma unroll
            for (int nt = 0; nt < 4; nt++) {
                const int code = code0 + (w & 1) * 64 + nt * 16 + r15;
                const float eq = esq[code];
                #pragma unroll
                for (int mt = 0; mt < 4; mt++)
                    #pragma unroll
                    for (int rg = 0; rg < 4; rg++) {
                        float sc = fmaf(-2.f, acc[mt][nt][rg], eq);
                        int sl = mt * 4 + rg;
                        if (sc < best[sl]) { best[sl] = sc; bidx[sl] = code; }
                    }
            }
            #pragma unroll
            for (int mt = 0; mt < 4; mt++)
                #pragma unroll
                for (int nt = 0; nt < 4; nt++) acc[mt][nt] = {0.f, 0.f, 0.f, 0.f};
        }
    }

    // block reduction: per row, top-2 over 32 contributors
    __syncthreads();
    float* smin = (float*)lds;           // [32][128] = 16KB
    int* sidx = (int*)(lds + 8192);      // [32][128] at +16KB
    const int cont = (w & 1) * 16 + r15;
    #pragma unroll
    for (int sl = 0; sl < 16; sl++) {
        int row = (w >> 1) * 64 + (sl >> 2) * 16 + quad * 4 + (sl & 3);
        smin[cont * 128 + row] = best[sl];
        sidx[cont * 128 + row] = bidx[sl];
    }
    __syncthreads();
    if (t < 128) {
        float m1 = FLT_MAX, m2 = FLT_MAX;
        int i1 = 0, i2 = 0;
        for (int c = 0; c < 32; c++) {
            float v = smin[c * 128 + t];
            int id = sidx[c * 128 + t];
            if (v < m1 || (v == m1 && id < i1)) {
                m2 = m1; i2 = i1; m1 = v; i1 = id;
            } else if (v < m2 || (v == m2 && id < i2)) {
                m2 = v; i2 = id;
            }
        }
        uint32_t pk = ((uint32_t)i1 << 13) | (uint32_t)(i2 & 8191);
        float4 out;
        out.x = m1; out.y = m2; out.z = __int_as_float((int)pk); out.w = 0.f;
        pcand[(size_t)(rt * 128 + t) * CS + cs] = out;
    }
}

__device__ __forceinline__ float wave_sum(float v) {
    #pragma unroll
    for (int o = 1; o < 64; o <<= 1) v += __shfl_xor(v, o);
    return v;
}

// margin-gated final: screened gap >> error bound -> trust screen (1 gather);
// else exact-fp32 rescore of all 2*CS candidates.
__global__ void vq_rescore(const float* __restrict__ X, const float* __restrict__ E,
                           const float4* __restrict__ pcand, float* __restrict__ out_q,
                           float* __restrict__ out_idx) {
    constexpr float MARGIN = 0.05f;  // screen error bound ~5e-4; 100x safety
    int row = blockIdx.x * 4 + (threadIdx.x >> 6);
    int lane = threadIdx.x & 63;

    int cand[2 * CS];
    float gm1 = FLT_MAX, gm2 = FLT_MAX;
    int gi1 = INT_MAX;
    #pragma unroll
    for (int s = 0; s < CS; s++) {
        float4 p = pcand[(size_t)row * CS + s];
        uint32_t pk = (uint32_t)__float_as_int(p.z);
        int i1 = (int)(pk >> 13), i2 = (int)(pk & 8191);
        cand[2 * s] = i1;
        cand[2 * s + 1] = i2;
        if (p.x < gm1 || (p.x == gm1 && i1 < gi1)) {
            gm2 = gm1; gm1 = p.x; gi1 = i1;
        } else if (p.x < gm2) gm2 = p.x;
        if (p.y < gm2) gm2 = p.y;
    }

    int besti = gi1;
    if (gm2 - gm1 <= MARGIN) {  // ambiguous: exact fp32 rescore (rare)
        float4 xv = ((const float4*)(X + (size_t)row * D))[lane];
        float xs = wave_sum(xv.x * xv.x + xv.y * xv.y + xv.z * xv.z + xv.w * xv.w);
        float bestv = FLT_MAX;
        besti = INT_MAX;
        #pragma unroll
        for (int c = 0; c < 2 * CS; c++) {
            int idx = cand[c];
            float4 e = ((const float4*)(E + (size_t)idx * D))[lane];
            float dp = wave_sum(xv.x * e.x + xv.y * e.y + xv.z * e.z + xv.w * e.w);
            float eq = wave_sum(e.x * e.x + e.y * e.y + e.z * e.z + e.w * e.w);
            float sc = (xs + eq) - 2.f * dp;
            if (sc < bestv || (sc == bestv && idx < besti)) { bestv = sc; besti = idx; }
        }
    }
    if (lane == 0) out_idx[row] = (float)besti;
    float4 bv = ((const float4*)(E + (size_t)besti * D))[lane];
    ((float4*)(out_q + (size_t)row * D))[lane] = bv;
}

// =======================================================================
// FALLBACK (proven R1 fp32 path) — used only if ws_size is too small
// =======================================================================
constexpr int BM = 128, BN = 128, DK = 32, KSPLIT = 8;
constexpr int KCHUNK = K / KSPLIT;
constexpr int LDX = BM + 4, LDE = BN + 4;

__global__ __launch_bounds__(256) void vq_main(
    const float* __restrict__ X, const float* __restrict__ E,
    const float* __restrict__ xsq, const float* __restrict__ esq,
    float* __restrict__ pmin, int* __restrict__ pidx) {
    __shared__ float sx[DK * LDX];
    __shared__ float se[DK * LDE];
    const int t = threadIdx.x;
    const int row0 = blockIdx.x * BM;
    const int kbeg = blockIdx.y * KCHUNK;
    const int lane = t & 63, wave = t >> 6;
    const int lm = lane >> 3, ln = lane & 7;
    const int mf = (wave >> 1) * 64 + lm * 8;
    const int nf = (wave & 1) * 64 + ln * 8;
    float xs[8];
    #pragma unroll
    for (int i = 0; i < 8; i++) xs[i] = xsq[row0 + mf + i];
    float rmin[8];
    int ridx[8];
    #pragma unroll
    for (int i = 0; i < 8; i++) { rmin[i] = FLT_MAX; ridx[i] = 0; }
    const int sm = t >> 3;
    const int sd = (t & 7) * 4;
    for (int kt = kbeg; kt < kbeg + KCHUNK; kt += BN) {
        float acc[8][8];
        #pragma unroll
        for (int i = 0; i < 8; i++)
            #pragma unroll
            for (int j = 0; j < 8; j++) acc[i][j] = 0.0f;
        for (int d0 = 0; d0 < D; d0 += DK) {
            __syncthreads();
            #pragma unroll
            for (int r = 0; r < 4; r++) {
                int row = sm + 32 * r;
                float4 v = *(const float4*)(X + (size_t)(row0 + row) * D + d0 + sd);
                sx[(sd + 0) * LDX + row] = v.x;
                sx[(sd + 1) * LDX + row] = v.y;
                sx[(sd + 2) * LDX + row] = v.z;
                sx[(sd + 3) * LDX + row] = v.w;
                float4 ww = *(const float4*)(E + (size_t)(kt + row) * D + d0 + sd);
                se[(sd + 0) * LDE + row] = ww.x;
                se[(sd + 1) * LDE + row] = ww.y;
                se[(sd + 2) * LDE + row] = ww.z;
                se[(sd + 3) * LDE + row] = ww.w;
            }
            __syncthreads();
            #pragma unroll
            for (int d = 0; d < DK; d++) {
                float4 a0 = *(const float4*)(sx + d * LDX + mf);
                float4 a1 = *(const float4*)(sx + d * LDX + mf + 4);
                float4 b0 = *(const float4*)(se + d * LDE + nf);
                float4 b1 = *(const float4*)(se + d * LDE + nf + 4);
                float a[8] = {a0.x, a0.y, a0.z, a0.w, a1.x, a1.y, a1.z, a1.w};
                float b[8] = {b0.x, b0.y, b0.z, b0.w, b1.x, b1.y, b1.z, b1.w};
                #pragma unroll
                for (int i = 0; i < 8; i++)
                    #pragma unroll
                    for (int j = 0; j < 8; j++) acc[i][j] += a[i] * b[j];
            }
        }
        float es[8];
        #pragma unroll
        for (int j = 0; j < 8; j++) es[j] = esq[kt + nf + j];
        #pragma unroll
        for (int i = 0; i < 8; i++)
            #pragma unroll
            for (int j = 0; j < 8; j++) {
                float s = (xs[i] + es[j]) - 2.0f * acc[i][j];
                if (s < rmin[i]) { rmin[i] = s; ridx[i] = kt + nf + j; }
            }
    }
    __syncthreads();
    float* redm = sx;
    int* redi = (int*)se;
    const int c = (wave & 1) * 8 + ln;
    #pragma unroll
    for (int i = 0; i < 8; i++) {
        int r = (wave >> 1) * 64 + lm * 8 + i;
        redm[r * 16 + c] = rmin[i];
        redi[r * 16 + c] = ridx[i];
    }
    __syncthreads();
    if (t < BM) {
        float bst = redm[t * 16];
        int bi = redi[t * 16];
        #pragma unroll
        for (int c2 = 1; c2 < 16; c2++) {
            float v = redm[t * 16 + c2];
            int id = redi[t * 16 + c2];
            if (v < bst || (v == bst && id < bi)) { bst = v; bi = id; }
        }
        pmin[(size_t)(row0 + t) * KSPLIT + blockIdx.y] = bst;
        pidx[(size_t)(row0 + t) * KSPLIT + blockIdx.y] = bi;
    }
}

__global__ void vq_final(const float* __restrict__ E, const float* __restrict__ pmin,
                         const int* __restrict__ pidx, float* __restrict__ out_q,
                         float* __restrict__ out_idx) {
    int row = blockIdx.x;
    int lane = threadIdx.x;
    float bst = pmin[(size_t)row * KSPLIT];
    int bi = pidx[(size_t)row * KSPLIT];
    #pragma unroll
    for (int s = 1; s < KSPLIT; s++) {
        float v = pmin[(size_t)row * KSPLIT + s];
        int id = pidx[(size_t)row * KSPLIT + s];
        if (v < bst || (v == bst && id < bi)) { bst = v; bi = id; }
    }
    if (lane == 0) out_idx[row] = (float)bi;
    float4 v = ((const float4*)(E + (size_t)bi * D))[lane];
    ((float4*)(out_q + (size_t)row * D))[lane] = v;
}

// =======================================================================
extern "C" void kernel_launch(void* const* d_in, const int* in_sizes, int n_in,
                              void* d_out, int out_size, void* d_ws, size_t ws_size,
                              hipStream_t stream) {
    const float* X = (const float*)d_in[0];  // [N, D]
    const float* E = (const float*)d_in[1];  // [K, D]
    float* out_q = (float*)d_out;
    float* out_idx = (float*)d_out + (size_t)N * D;

    // fast-path ws: Xh(8M) Xl(8M) Eh(4M) El(4M) esq(32K) pcand(N*CS*16 = 1M)
    const size_t need = (size_t)24 * 1024 * 1024 + 32768 + (size_t)N * CS * 16;
    if (ws_size >= need) {
        _Float16* Xh = (_Float16*)d_ws;
        _Float16* Xl = Xh + (size_t)N * D;
        _Float16* Eh = Xl + (size_t)N * D;
        _Float16* El = Eh + (size_t)K * D;
        float* esq = (float*)(El + (size_t)K * D);
        float4* pcand = (float4*)(esq + K);

        vq_prep<<<(N + K) * 32 / 256, 256, 0, stream>>>(X, E, Xh, Xl, Eh, El, esq);
        dim3 grid(N / 128, CS);
        vq_mfma<<<grid, 256, 0, stream>>>(Xh, Xl, Eh, El, esq, pcand);
        vq_rescore<<<N / 4, 256, 0, stream>>>(X, E, pcand, out_q, out_idx);
    } else {
        float* esq = (float*)d_ws;
        float* xsq = esq + K;
        float* pmin = xsq + N;
        int* pidx = (int*)(pmin + (size_t)N * KSPLIT);
        vq_rowsq<<<K, 64, 0, stream>>>(E, esq);
        vq_rowsq<<<N, 64, 0, stream>>>(X, xsq);
        dim3 grid(N / BM, KSPLIT);
        vq_main<<<grid, 256, 0, stream>>>(X, E, xsq, esq, pmin, pidx);
        vq_final<<<N, 64, 0, stream>>>(E, pmin, pidx, out_q, out_idx);
    }
}

// Round 5
// 246.410 us; speedup vs baseline: 1.2231x; 1.0895x over previous
//
#include <hip/hip_runtime.h>
#include <float.h>
#include <limits.h>
#include <stdint.h>

constexpr int N = 16384;
constexpr int K = 8192;
constexpr int D = 256;

typedef _Float16 half8_t __attribute__((ext_vector_type(8)));
typedef float float4_t __attribute__((ext_vector_type(4)));

// ---------------- fallback helper: row sum-of-squares (one wave per row) ----
__global__ void vq_rowsq(const float* __restrict__ A, float* __restrict__ out) {
    int row = blockIdx.x;
    int lane = threadIdx.x;  // 64
    float4 v = ((const float4*)(A + (size_t)row * D))[lane];
    float s = v.x * v.x + v.y * v.y + v.z * v.z + v.w * v.w;
    #pragma unroll
    for (int o = 32; o > 0; o >>= 1) s += __shfl_down(s, o);
    if (lane == 0) out[row] = s;
}

// =======================================================================
// FAST PATH: f16 2-pass MFMA screen (xh·eh + xh·el) + margin-gated rescore
// =======================================================================
// LDS fragment layout is LANE-LINEAR by construction: a region is a list of
// 16B chunks in the exact order frag-reads consume them (slot = group*64 +
// lane), so ds_read_b128 and global_load_lds are conflict-free, no swizzle.
// X region (per rowtile rt, 32-dim step ds): 512 chunks, slot = (lr>>4)*64 +
// q*16 + (lr&15).  E region (per 64-code tile et, ds): 256 chunks, slot =
// (lc>>4)*64 + q*16 + (lc&15).

__global__ void vq_prep(const float* __restrict__ X, const float* __restrict__ E,
                        _Float16* __restrict__ Xh, _Float16* __restrict__ Eh,
                        _Float16* __restrict__ El, float* __restrict__ esq) {
    int c = blockIdx.x * 256 + threadIdx.x;
    const int XCH = N * 32;  // X chunk count; XCH % 256 == 0 so blocks don't mix
    if (c < XCH) {
        int r = c >> 5, q8 = c & 31;
        int ds = q8 >> 2, q = q8 & 3;
        int rt = r >> 7, lr = r & 127;
        int slot = ((lr >> 4) << 6) + (q << 4) + (lr & 15);
        size_t dst = ((size_t)(rt * 8 + ds) * 512 + slot) * 8;
        const float4* s4 = (const float4*)(X + (size_t)r * D + q8 * 8);
        float4 v0 = s4[0], v1 = s4[1];
        float x[8] = {v0.x, v0.y, v0.z, v0.w, v1.x, v1.y, v1.z, v1.w};
        half8_t hh;
        #pragma unroll
        for (int i = 0; i < 8; i++) hh[i] = (_Float16)x[i];  // hi only; lo dropped (2-pass)
        *(half8_t*)(Xh + dst) = hh;
    } else {
        int cc = c - XCH;
        int r = cc >> 5, q8 = cc & 31;
        int ds = q8 >> 2, q = q8 & 3;
        int et = r >> 6, lc = r & 63;
        int slot = ((lc >> 4) << 6) + (q << 4) + (lc & 15);
        size_t dst = ((size_t)(et * 8 + ds) * 256 + slot) * 8;
        const float4* s4 = (const float4*)(E + (size_t)r * D + q8 * 8);
        float4 v0 = s4[0], v1 = s4[1];
        float x[8] = {v0.x, v0.y, v0.z, v0.w, v1.x, v1.y, v1.z, v1.w};
        half8_t hh, ll;
        float sq = 0.f;
        #pragma unroll
        for (int i = 0; i < 8; i++) {
            _Float16 hi = (_Float16)x[i];
            hh[i] = hi;
            ll[i] = (_Float16)(x[i] - (float)hi);  // exact in fp32
            sq += x[i] * x[i];
        }
        *(half8_t*)(Eh + dst) = hh;
        *(half8_t*)(El + dst) = ll;
        // 32 consecutive threads share a code row; reduce within the 32-group
        #pragma unroll
        for (int o = 16; o > 0; o >>= 1) sq += __shfl_xor(sq, o);
        if ((threadIdx.x & 31) == 0) esq[r] = sq;
    }
}

__device__ __forceinline__ void ldg_lds16(const _Float16* g, _Float16* l) {
    __builtin_amdgcn_global_load_lds(
        (const __attribute__((address_space(1))) unsigned int*)g,
        (__attribute__((address_space(3))) unsigned int*)l, 16, 0, 0);
}

constexpr int CS = 8;             // grid = 128 rowtiles x 8 = 1024 blocks = 4/CU exact
constexpr int KT = (K / 64) / CS; // 16 64-code tiles per block
constexpr int NSTEP = KT * 8;     // 128 flattened (ctile, ds) steps

// block: 128 thr = 2 waves, tile 128 rows x 64 codes; wave w owns rows w*64..+63.
// LDS double buffer: per step X(512 chunks)|Eh(256)|El(256) = 16KB, x2 = 32KB.
// Pipeline: barrier -> issue stage(s+1) -> ds_read+MFMA(s).
__global__ __launch_bounds__(128, 2) void vq_mfma(
    const _Float16* __restrict__ Xh, const _Float16* __restrict__ Eh,
    const _Float16* __restrict__ El, const float* __restrict__ esq,
    float4* __restrict__ pcand) {
    __shared__ _Float16 lds[16384];  // 32KB = 2 bufs x 1024 chunks x 16B

    const int t = threadIdx.x, w = t >> 6, lane = t & 63;
    const int rt = blockIdx.x;  // row tile 0..127
    const int cs = blockIdx.y;  // code split 0..7
    const int c15 = lane & 15, quad = lane >> 4;

    float best[16];
    int bidx[16];
    #pragma unroll
    for (int i = 0; i < 16; i++) { best[i] = FLT_MAX; bidx[i] = 0; }

    // wave 0 stages the X region (8 instr), wave 1 stages Eh+El (4+4 instr)
    auto stage = [&](int s) {
        const int ct = cs * KT + (s >> 3), ds = s & 7;
        const int base = (s & 1) * 1024;  // chunk units
        if (w == 0) {
            const _Float16* src = Xh + (size_t)(rt * 8 + ds) * 512 * 8;
            _Float16* dst = lds + (size_t)base * 8;
            #pragma unroll
            for (int i = 0; i < 8; i++)
                ldg_lds16(src + (size_t)(i * 64 + lane) * 8, dst + i * 512);
        } else {
            const _Float16* srch = Eh + (size_t)(ct * 8 + ds) * 256 * 8;
            const _Float16* srcl = El + (size_t)(ct * 8 + ds) * 256 * 8;
            _Float16* dsth = lds + (size_t)(base + 512) * 8;
            _Float16* dstl = lds + (size_t)(base + 768) * 8;
            #pragma unroll
            for (int i = 0; i < 4; i++) {
                ldg_lds16(srch + (size_t)(i * 64 + lane) * 8, dsth + i * 512);
                ldg_lds16(srcl + (size_t)(i * 64 + lane) * 8, dstl + i * 512);
            }
        }
    };

    stage(0);

    float4_t acc[4][4];
    #pragma unroll
    for (int mt = 0; mt < 4; mt++)
        #pragma unroll
        for (int nt = 0; nt < 4; nt++) acc[mt][nt] = {0.f, 0.f, 0.f, 0.f};

    const half8_t* C = (const half8_t*)lds;

    for (int s = 0; s < NSTEP; s++) {
        __syncthreads();  // drains stage(s), issued one full step earlier (except s=0)
        if (s + 1 < NSTEP) stage(s + 1);

        const int b = (s & 1) * 1024;
        half8_t Ah[4], Bh[4], Bl[4];
        #pragma unroll
        for (int mt = 0; mt < 4; mt++) Ah[mt] = C[b + w * 256 + mt * 64 + lane];
        #pragma unroll
        for (int nt = 0; nt < 4; nt++) {
            Bh[nt] = C[b + 512 + nt * 64 + lane];
            Bl[nt] = C[b + 768 + nt * 64 + lane];
        }
        #pragma unroll
        for (int mt = 0; mt < 4; mt++)
            #pragma unroll
            for (int nt = 0; nt < 4; nt++) {
                acc[mt][nt] = __builtin_amdgcn_mfma_f32_16x16x32_f16(
                    Ah[mt], Bh[nt], acc[mt][nt], 0, 0, 0);
                acc[mt][nt] = __builtin_amdgcn_mfma_f32_16x16x32_f16(
                    Ah[mt], Bl[nt], acc[mt][nt], 0, 0, 0);
            }

        if ((s & 7) == 7) {  // ctile finished: epilogue + acc reset
            const int code0 = (cs * KT + (s >> 3)) * 64;
            #pragma unroll
            for (int nt = 0; nt < 4; nt++) {
                const int code = code0 + nt * 16 + c15;
                const float eq = esq[code];
                #pragma unroll
                for (int mt = 0; mt < 4; mt++)
                    #pragma unroll
                    for (int rg = 0; rg < 4; rg++) {
                        float sc = fmaf(-2.f, acc[mt][nt][rg], eq);
                        int sl = mt * 4 + rg;
                        if (sc < best[sl]) { best[sl] = sc; bidx[sl] = code; }
                    }
            }
            #pragma unroll
            for (int mt = 0; mt < 4; mt++)
                #pragma unroll
                for (int nt = 0; nt < 4; nt++) acc[mt][nt] = {0.f, 0.f, 0.f, 0.f};
        }
    }

    // per-row top-2 over the 16 lane-contributors (c15 groups)
    __syncthreads();
    float* smin = (float*)lds;               // [16][132] floats
    int* sidx = (int*)lds + 16 * 132;        // [16][132] ints (starts at 8448B)
    #pragma unroll
    for (int sl = 0; sl < 16; sl++) {
        int row = w * 64 + (sl >> 2) * 16 + quad * 4 + (sl & 3);
        smin[c15 * 132 + row] = best[sl];
        sidx[c15 * 132 + row] = bidx[sl];
    }
    __syncthreads();
    {
        float m1 = FLT_MAX, m2 = FLT_MAX;
        int i1 = 0, i2 = 0;
        #pragma unroll 4
        for (int c = 0; c < 16; c++) {
            float v = smin[c * 132 + t];
            int id = sidx[c * 132 + t];
            if (v < m1 || (v == m1 && id < i1)) {
                m2 = m1; i2 = i1; m1 = v; i1 = id;
            } else if (v < m2 || (v == m2 && id < i2)) {
                m2 = v; i2 = id;
            }
        }
        uint32_t pk = ((uint32_t)i1 << 13) | (uint32_t)(i2 & 8191);
        float4 out;
        out.x = m1; out.y = m2; out.z = __int_as_float((int)pk); out.w = 0.f;
        pcand[(size_t)(rt * 128 + t) * CS + cs] = out;
    }
}

__device__ __forceinline__ float wave_sum(float v) {
    #pragma unroll
    for (int o = 1; o < 64; o <<= 1) v += __shfl_xor(v, o);
    return v;
}

// margin-gated final: screened gap >> screen-error bound -> trust screen;
// else exact-fp32 rescore of all 2*CS candidates (rare).
__global__ void vq_rescore(const float* __restrict__ X, const float* __restrict__ E,
                           const float4* __restrict__ pcand, float* __restrict__ out_q,
                           float* __restrict__ out_idx) {
    constexpr float MARGIN = 0.25f;  // screen |err| <= ~2.5e-2; 10x safety
    int row = blockIdx.x * 4 + (threadIdx.x >> 6);
    int lane = threadIdx.x & 63;

    int cand[2 * CS];
    float gm1 = FLT_MAX, gm2 = FLT_MAX;
    int gi1 = INT_MAX;
    #pragma unroll
    for (int s = 0; s < CS; s++) {
        float4 p = pcand[(size_t)row * CS + s];
        uint32_t pk = (uint32_t)__float_as_int(p.z);
        int i1 = (int)(pk >> 13), i2 = (int)(pk & 8191);
        cand[2 * s] = i1;
        cand[2 * s + 1] = i2;
        if (p.x < gm1 || (p.x == gm1 && i1 < gi1)) {
            gm2 = gm1; gm1 = p.x; gi1 = i1;
        } else if (p.x < gm2) gm2 = p.x;
        if (p.y < gm2) gm2 = p.y;
    }

    int besti = gi1;
    if (gm2 - gm1 <= MARGIN) {  // ambiguous: exact fp32 rescore
        float4 xv = ((const float4*)(X + (size_t)row * D))[lane];
        float xs = wave_sum(xv.x * xv.x + xv.y * xv.y + xv.z * xv.z + xv.w * xv.w);
        float bestv = FLT_MAX;
        besti = INT_MAX;
        #pragma unroll
        for (int c = 0; c < 2 * CS; c++) {
            int idx = cand[c];
            float4 e = ((const float4*)(E + (size_t)idx * D))[lane];
            float dp = wave_sum(xv.x * e.x + xv.y * e.y + xv.z * e.z + xv.w * e.w);
            float eq = wave_sum(e.x * e.x + e.y * e.y + e.z * e.z + e.w * e.w);
            float sc = (xs + eq) - 2.f * dp;
            if (sc < bestv || (sc == bestv && idx < besti)) { bestv = sc; besti = idx; }
        }
    }
    if (lane == 0) out_idx[row] = (float)besti;
    float4 bv = ((const float4*)(E + (size_t)besti * D))[lane];
    ((float4*)(out_q + (size_t)row * D))[lane] = bv;
}

// =======================================================================
// FALLBACK (proven R1 fp32 path) — used only if ws_size is too small
// =======================================================================
constexpr int BM = 128, BN = 128, DK = 32, KSPLIT = 8;
constexpr int KCHUNK = K / KSPLIT;
constexpr int LDX = BM + 4, LDE = BN + 4;

__global__ __launch_bounds__(256) void vq_main(
    const float* __restrict__ X, const float* __restrict__ E,
    const float* __restrict__ xsq, const float* __restrict__ esq,
    float* __restrict__ pmin, int* __restrict__ pidx) {
    __shared__ float sx[DK * LDX];
    __shared__ float se[DK * LDE];
    const int t = threadIdx.x;
    const int row0 = blockIdx.x * BM;
    const int kbeg = blockIdx.y * KCHUNK;
    const int lane = t & 63, wave = t >> 6;
    const int lm = lane >> 3, ln = lane & 7;
    const int mf = (wave >> 1) * 64 + lm * 8;
    const int nf = (wave & 1) * 64 + ln * 8;
    float xs[8];
    #pragma unroll
    for (int i = 0; i < 8; i++) xs[i] = xsq[row0 + mf + i];
    float rmin[8];
    int ridx[8];
    #pragma unroll
    for (int i = 0; i < 8; i++) { rmin[i] = FLT_MAX; ridx[i] = 0; }
    const int sm = t >> 3;
    const int sd = (t & 7) * 4;
    for (int kt = kbeg; kt < kbeg + KCHUNK; kt += BN) {
        float acc[8][8];
        #pragma unroll
        for (int i = 0; i < 8; i++)
            #pragma unroll
            for (int j = 0; j < 8; j++) acc[i][j] = 0.0f;
        for (int d0 = 0; d0 < D; d0 += DK) {
            __syncthreads();
            #pragma unroll
            for (int r = 0; r < 4; r++) {
                int row = sm + 32 * r;
                float4 v = *(const float4*)(X + (size_t)(row0 + row) * D + d0 + sd);
                sx[(sd + 0) * LDX + row] = v.x;
                sx[(sd + 1) * LDX + row] = v.y;
                sx[(sd + 2) * LDX + row] = v.z;
                sx[(sd + 3) * LDX + row] = v.w;
                float4 ww = *(const float4*)(E + (size_t)(kt + row) * D + d0 + sd);
                se[(sd + 0) * LDE + row] = ww.x;
                se[(sd + 1) * LDE + row] = ww.y;
                se[(sd + 2) * LDE + row] = ww.z;
                se[(sd + 3) * LDE + row] = ww.w;
            }
            __syncthreads();
            #pragma unroll
            for (int d = 0; d < DK; d++) {
                float4 a0 = *(const float4*)(sx + d * LDX + mf);
                float4 a1 = *(const float4*)(sx + d * LDX + mf + 4);
                float4 b0 = *(const float4*)(se + d * LDE + nf);
                float4 b1 = *(const float4*)(se + d * LDE + nf + 4);
                float a[8] = {a0.x, a0.y, a0.z, a0.w, a1.x, a1.y, a1.z, a1.w};
                float b[8] = {b0.x, b0.y, b0.z, b0.w, b1.x, b1.y, b1.z, b1.w};
                #pragma unroll
                for (int i = 0; i < 8; i++)
                    #pragma unroll
                    for (int j = 0; j < 8; j++) acc[i][j] += a[i] * b[j];
            }
        }
        float es[8];
        #pragma unroll
        for (int j = 0; j < 8; j++) es[j] = esq[kt + nf + j];
        #pragma unroll
        for (int i = 0; i < 8; i++)
            #pragma unroll
            for (int j = 0; j < 8; j++) {
                float s = (xs[i] + es[j]) - 2.0f * acc[i][j];
                if (s < rmin[i]) { rmin[i] = s; ridx[i] = kt + nf + j; }
            }
    }
    __syncthreads();
    float* redm = sx;
    int* redi = (int*)se;
    const int c = (wave & 1) * 8 + ln;
    #pragma unroll
    for (int i = 0; i < 8; i++) {
        int r = (wave >> 1) * 64 + lm * 8 + i;
        redm[r * 16 + c] = rmin[i];
        redi[r * 16 + c] = ridx[i];
    }
    __syncthreads();
    if (t < BM) {
        float bst = redm[t * 16];
        int bi = redi[t * 16];
        #pragma unroll
        for (int c2 = 1; c2 < 16; c2++) {
            float v = redm[t * 16 + c2];
            int id = redi[t * 16 + c2];
            if (v < bst || (v == bst && id < bi)) { bst = v; bi = id; }
        }
        pmin[(size_t)(row0 + t) * KSPLIT + blockIdx.y] = bst;
        pidx[(size_t)(row0 + t) * KSPLIT + blockIdx.y] = bi;
    }
}

__global__ void vq_final(const float* __restrict__ E, const float* __restrict__ pmin,
                         const int* __restrict__ pidx, float* __restrict__ out_q,
                         float* __restrict__ out_idx) {
    int row = blockIdx.x;
    int lane = threadIdx.x;
    float bst = pmin[(size_t)row * KSPLIT];
    int bi = pidx[(size_t)row * KSPLIT];
    #pragma unroll
    for (int s = 1; s < KSPLIT; s++) {
        float v = pmin[(size_t)row * KSPLIT + s];
        int id = pidx[(size_t)row * KSPLIT + s];
        if (v < bst || (v == bst && id < bi)) { bst = v; bi = id; }
    }
    if (lane == 0) out_idx[row] = (float)bi;
    float4 v = ((const float4*)(E + (size_t)bi * D))[lane];
    ((float4*)(out_q + (size_t)row * D))[lane] = v;
}

// =======================================================================
extern "C" void kernel_launch(void* const* d_in, const int* in_sizes, int n_in,
                              void* d_out, int out_size, void* d_ws, size_t ws_size,
                              hipStream_t stream) {
    const float* X = (const float*)d_in[0];  // [N, D]
    const float* E = (const float*)d_in[1];  // [K, D]
    float* out_q = (float*)d_out;
    float* out_idx = (float*)d_out + (size_t)N * D;

    // fast-path ws: Xh(8M) Eh(4M) El(4M) esq(32K) pcand(N*CS*16 = 2M) ~ 18MB
    const size_t need = (size_t)16 * 1024 * 1024 + 32768 + (size_t)N * CS * 16;
    if (ws_size >= need) {
        _Float16* Xh = (_Float16*)d_ws;
        _Float16* Eh = Xh + (size_t)N * D;
        _Float16* El = Eh + (size_t)K * D;
        float* esq = (float*)(El + (size_t)K * D);
        float4* pcand = (float4*)(esq + K);

        vq_prep<<<(N + K) * 32 / 256, 256, 0, stream>>>(X, E, Xh, Eh, El, esq);
        dim3 grid(N / 128, CS);
        vq_mfma<<<grid, 128, 0, stream>>>(Xh, Eh, El, esq, pcand);
        vq_rescore<<<N / 4, 256, 0, stream>>>(X, E, pcand, out_q, out_idx);
    } else {
        float* esq = (float*)d_ws;
        float* xsq = esq + K;
        float* pmin = xsq + N;
        int* pidx = (int*)(pmin + (size_t)N * KSPLIT);
        vq_rowsq<<<K, 64, 0, stream>>>(E, esq);
        vq_rowsq<<<N, 64, 0, stream>>>(X, xsq);
        dim3 grid(N / BM, KSPLIT);
        vq_main<<<grid, 256, 0, stream>>>(X, E, xsq, esq, pmin, pidx);
        vq_final<<<N, 64, 0, stream>>>(E, pmin, pidx, out_q, out_idx);
    }
}

// Round 6
// 216.421 us; speedup vs baseline: 1.3926x; 1.1386x over previous
//
#include <hip/hip_runtime.h>
#include <float.h>
#include <limits.h>
#include <stdint.h>

constexpr int N = 16384;
constexpr int K = 8192;
constexpr int D = 256;

typedef _Float16 half8_t __attribute__((ext_vector_type(8)));
typedef float float4_t __attribute__((ext_vector_type(4)));

// ---------------- row sum-of-squares (one wave per row) ----------------
__global__ void vq_rowsq(const float* __restrict__ A, float* __restrict__ out) {
    int row = blockIdx.x;
    int lane = threadIdx.x;  // 64
    float4 v = ((const float4*)(A + (size_t)row * D))[lane];
    float s = v.x * v.x + v.y * v.y + v.z * v.z + v.w * v.w;
    #pragma unroll
    for (int o = 32; o > 0; o >>= 1) s += __shfl_down(s, o);
    if (lane == 0) out[row] = s;
}

// =======================================================================
// FAST PATH: 1-pass f16-hi MFMA screen + margin-gated exact fp32 rescore
// =======================================================================
// Pre-tiled lane-linear layout. X region (rt,ds) = 512 16B-chunks:
// slot = (lr>>4)*64 + q*16 + (lr&15)  (lr=local row 0..127, q=8-dim chunk).
// E region (et,ds) = 256 chunks: slot = (lc>>4)*64 + q*16 + (lc&15).
// Staging (global_load_lds) and fragment ds_read_b128 are both lane-linear
// by construction -> zero bank conflicts (verified R5).

// Coalesced prep: thread c WRITES chunk c (linear 16B stores); reads decode
// the (row, dim) for that slot. One wave reads 16 rows x 128B full lines.
__global__ void vq_prep(const float* __restrict__ X, const float* __restrict__ E,
                        _Float16* __restrict__ Xh, _Float16* __restrict__ Eh) {
    int c = blockIdx.x * 256 + threadIdx.x;
    const int XCH = N * 32;  // X chunks (% 256 == 0)
    const float* src;
    _Float16* dst;
    if (c < XCH) {
        int region = c >> 9, slot = c & 511;
        int rt = region >> 3, ds = region & 7;
        int g = slot >> 6, q = (slot >> 4) & 3, r15 = slot & 15;
        int row = rt * 128 + g * 16 + r15;
        src = X + (size_t)row * D + ds * 32 + q * 8;
        dst = Xh + (size_t)c * 8;
    } else {
        int cc = c - XCH;
        int region = cc >> 8, slot = cc & 255;
        int et = region >> 3, ds = region & 7;
        int g = slot >> 6, q = (slot >> 4) & 3, r15 = slot & 15;
        int code = et * 64 + g * 16 + r15;
        src = E + (size_t)code * D + ds * 32 + q * 8;
        dst = Eh + (size_t)cc * 8;
    }
    float4 v0 = ((const float4*)src)[0], v1 = ((const float4*)src)[1];
    float x[8] = {v0.x, v0.y, v0.z, v0.w, v1.x, v1.y, v1.z, v1.w};
    half8_t hh;
    #pragma unroll
    for (int i = 0; i < 8; i++) hh[i] = (_Float16)x[i];
    *(half8_t*)dst = hh;
}

__device__ __forceinline__ void ldg_lds16(const _Float16* g, _Float16* l) {
    __builtin_amdgcn_global_load_lds(
        (const __attribute__((address_space(1))) unsigned int*)g,
        (__attribute__((address_space(3))) unsigned int*)l, 16, 0, 0);
}

constexpr int CS = 16;            // grid = 16 x 128 = 2048 blocks (8/CU queued)
constexpr int KT = (K / 64) / CS; // 8 64-code tiles per block
constexpr int NSTEP = KT * 8;     // 64 flattened (ctile, ds) steps

// block: 128 thr = 2 waves; tile 128 rows x 64 codes; wave w owns rows w*64..+63.
// LDS: per step X(512 chunks, 8KB) + E(256, 4KB) = 12KB, dbuf = 24KB -> 6 blk/CU.
__global__ __launch_bounds__(128, 3) void vq_mfma(
    const _Float16* __restrict__ Xh, const _Float16* __restrict__ Eh,
    const float* __restrict__ esq, float4* __restrict__ pcand) {
    __shared__ _Float16 lds[12288];  // 24KB = 2 bufs x 768 chunks

    const int t = threadIdx.x, w = t >> 6, lane = t & 63;
    const int cs = blockIdx.x;  // code split 0..15 (x-major: same-rt blocks adjacent)
    const int rt = blockIdx.y;  // row tile 0..127
    const int c15 = lane & 15, quad = lane >> 4;

    float best[16];
    int bidx[16];
    #pragma unroll
    for (int i = 0; i < 16; i++) { best[i] = FLT_MAX; bidx[i] = 0; }

    // wave 0 stages X (8 chunks/lane), wave 1 stages E (4 chunks/lane)
    auto stage = [&](int s) {
        const int ct = cs * KT + (s >> 3), ds = s & 7;
        const int base = (s & 1) * 768;  // chunk units
        if (w == 0) {
            const _Float16* src = Xh + (size_t)(rt * 8 + ds) * 512 * 8;
            _Float16* dst = lds + (size_t)base * 8;
            #pragma unroll
            for (int i = 0; i < 8; i++)
                ldg_lds16(src + (size_t)(i * 64 + lane) * 8, dst + i * 512);
        } else {
            const _Float16* src = Eh + (size_t)(ct * 8 + ds) * 256 * 8;
            _Float16* dst = lds + (size_t)(base + 512) * 8;
            #pragma unroll
            for (int i = 0; i < 4; i++)
                ldg_lds16(src + (size_t)(i * 64 + lane) * 8, dst + i * 512);
        }
    };

    stage(0);

    float4_t acc[4][4];
    #pragma unroll
    for (int mt = 0; mt < 4; mt++)
        #pragma unroll
        for (int nt = 0; nt < 4; nt++) acc[mt][nt] = {0.f, 0.f, 0.f, 0.f};

    const half8_t* C = (const half8_t*)lds;

    for (int s = 0; s < NSTEP; s++) {
        __syncthreads();  // drains stage(s), issued one full step earlier
        if (s + 1 < NSTEP) stage(s + 1);

        const int b = (s & 1) * 768;
        half8_t Ah[4], Bh[4];
        #pragma unroll
        for (int mt = 0; mt < 4; mt++) Ah[mt] = C[b + w * 256 + mt * 64 + lane];
        #pragma unroll
        for (int nt = 0; nt < 4; nt++) Bh[nt] = C[b + 512 + nt * 64 + lane];
        #pragma unroll
        for (int mt = 0; mt < 4; mt++)
            #pragma unroll
            for (int nt = 0; nt < 4; nt++)
                acc[mt][nt] = __builtin_amdgcn_mfma_f32_16x16x32_f16(
                    Ah[mt], Bh[nt], acc[mt][nt], 0, 0, 0);

        if ((s & 7) == 7) {  // ctile finished: epilogue + acc reset
            const int code0 = (cs * KT + (s >> 3)) * 64;
            #pragma unroll
            for (int nt = 0; nt < 4; nt++) {
                const int code = code0 + nt * 16 + c15;
                const float eq = esq[code];
                #pragma unroll
                for (int mt = 0; mt < 4; mt++)
                    #pragma unroll
                    for (int rg = 0; rg < 4; rg++) {
                        float sc = fmaf(-2.f, acc[mt][nt][rg], eq);
                        int sl = mt * 4 + rg;
                        if (sc < best[sl]) { best[sl] = sc; bidx[sl] = code; }
                    }
            }
            #pragma unroll
            for (int mt = 0; mt < 4; mt++)
                #pragma unroll
                for (int nt = 0; nt < 4; nt++) acc[mt][nt] = {0.f, 0.f, 0.f, 0.f};
        }
    }

    // per-row top-2 over the 16 c15 contributors
    __syncthreads();
    float* smin = (float*)lds;               // [16][132] floats (8448 B)
    int* sidx = (int*)lds + 16 * 132;        // [16][132] ints
    #pragma unroll
    for (int sl = 0; sl < 16; sl++) {
        int row = w * 64 + (sl >> 2) * 16 + quad * 4 + (sl & 3);
        smin[c15 * 132 + row] = best[sl];
        sidx[c15 * 132 + row] = bidx[sl];
    }
    __syncthreads();
    {
        float m1 = FLT_MAX, m2 = FLT_MAX;
        int i1 = 0, i2 = 0;
        #pragma unroll 4
        for (int c = 0; c < 16; c++) {
            float v = smin[c * 132 + t];
            int id = sidx[c * 132 + t];
            if (v < m1 || (v == m1 && id < i1)) {
                m2 = m1; i2 = i1; m1 = v; i1 = id;
            } else if (v < m2 || (v == m2 && id < i2)) {
                m2 = v; i2 = id;
            }
        }
        uint32_t pk = ((uint32_t)i1 << 13) | (uint32_t)(i2 & 8191);
        float4 out;
        out.x = m1; out.y = m2; out.z = __int_as_float((int)pk); out.w = 0.f;
        pcand[(size_t)(rt * 128 + t) * CS + cs] = out;
    }
}

__device__ __forceinline__ float wave_sum(float v) {
    #pragma unroll
    for (int o = 1; o < 64; o <<= 1) v += __shfl_xor(v, o);
    return v;
}

// margin-gated final: screened gap > margin -> trust screen (1 gather);
// else exact-fp32 rescore of all 2*CS candidates (~4% of rows).
__global__ void vq_rescore(const float* __restrict__ X, const float* __restrict__ E,
                           const float4* __restrict__ pcand, float* __restrict__ out_q,
                           float* __restrict__ out_idx) {
    constexpr float MARGIN = 0.5f;  // screen max|err| ~0.07; 28 sigma gate
    int row = blockIdx.x * 4 + (threadIdx.x >> 6);
    int lane = threadIdx.x & 63;

    int cand[2 * CS];
    float gm1 = FLT_MAX, gm2 = FLT_MAX;
    int gi1 = INT_MAX;
    #pragma unroll
    for (int s = 0; s < CS; s++) {
        float4 p = pcand[(size_t)row * CS + s];
        uint32_t pk = (uint32_t)__float_as_int(p.z);
        int i1 = (int)(pk >> 13), i2 = (int)(pk & 8191);
        cand[2 * s] = i1;
        cand[2 * s + 1] = i2;
        if (p.x < gm1 || (p.x == gm1 && i1 < gi1)) {
            gm2 = gm1; gm1 = p.x; gi1 = i1;
        } else if (p.x < gm2) gm2 = p.x;
        if (p.y < gm2) gm2 = p.y;
    }

    int besti = gi1;
    if (gm2 - gm1 <= MARGIN) {  // ambiguous: exact fp32 rescore
        float4 xv = ((const float4*)(X + (size_t)row * D))[lane];
        float xs = wave_sum(xv.x * xv.x + xv.y * xv.y + xv.z * xv.z + xv.w * xv.w);
        float bestv = FLT_MAX;
        besti = INT_MAX;
        for (int c = 0; c < 2 * CS; c++) {
            int idx = cand[c];
            float4 e = ((const float4*)(E + (size_t)idx * D))[lane];
            float dp = wave_sum(xv.x * e.x + xv.y * e.y + xv.z * e.z + xv.w * e.w);
            float eq = wave_sum(e.x * e.x + e.y * e.y + e.z * e.z + e.w * e.w);
            float sc = (xs + eq) - 2.f * dp;
            if (sc < bestv || (sc == bestv && idx < besti)) { bestv = sc; besti = idx; }
        }
    }
    if (lane == 0) out_idx[row] = (float)besti;
    float4 bv = ((const float4*)(E + (size_t)besti * D))[lane];
    ((float4*)(out_q + (size_t)row * D))[lane] = bv;
}

// =======================================================================
// FALLBACK (proven R1 fp32 path) — used only if ws_size is too small
// =======================================================================
constexpr int BM = 128, BN = 128, DK = 32, KSPLIT = 8;
constexpr int KCHUNK = K / KSPLIT;
constexpr int LDX = BM + 4, LDE = BN + 4;

__global__ __launch_bounds__(256) void vq_main(
    const float* __restrict__ X, const float* __restrict__ E,
    const float* __restrict__ xsq, const float* __restrict__ esq,
    float* __restrict__ pmin, int* __restrict__ pidx) {
    __shared__ float sx[DK * LDX];
    __shared__ float se[DK * LDE];
    const int t = threadIdx.x;
    const int row0 = blockIdx.x * BM;
    const int kbeg = blockIdx.y * KCHUNK;
    const int lane = t & 63, wave = t >> 6;
    const int lm = lane >> 3, ln = lane & 7;
    const int mf = (wave >> 1) * 64 + lm * 8;
    const int nf = (wave & 1) * 64 + ln * 8;
    float xs[8];
    #pragma unroll
    for (int i = 0; i < 8; i++) xs[i] = xsq[row0 + mf + i];
    float rmin[8];
    int ridx[8];
    #pragma unroll
    for (int i = 0; i < 8; i++) { rmin[i] = FLT_MAX; ridx[i] = 0; }
    const int sm = t >> 3;
    const int sd = (t & 7) * 4;
    for (int kt = kbeg; kt < kbeg + KCHUNK; kt += BN) {
        float acc[8][8];
        #pragma unroll
        for (int i = 0; i < 8; i++)
            #pragma unroll
            for (int j = 0; j < 8; j++) acc[i][j] = 0.0f;
        for (int d0 = 0; d0 < D; d0 += DK) {
            __syncthreads();
            #pragma unroll
            for (int r = 0; r < 4; r++) {
                int row = sm + 32 * r;
                float4 v = *(const float4*)(X + (size_t)(row0 + row) * D + d0 + sd);
                sx[(sd + 0) * LDX + row] = v.x;
                sx[(sd + 1) * LDX + row] = v.y;
                sx[(sd + 2) * LDX + row] = v.z;
                sx[(sd + 3) * LDX + row] = v.w;
                float4 ww = *(const float4*)(E + (size_t)(kt + row) * D + d0 + sd);
                se[(sd + 0) * LDE + row] = ww.x;
                se[(sd + 1) * LDE + row] = ww.y;
                se[(sd + 2) * LDE + row] = ww.z;
                se[(sd + 3) * LDE + row] = ww.w;
            }
            __syncthreads();
            #pragma unroll
            for (int d = 0; d < DK; d++) {
                float4 a0 = *(const float4*)(sx + d * LDX + mf);
                float4 a1 = *(const float4*)(sx + d * LDX + mf + 4);
                float4 b0 = *(const float4*)(se + d * LDE + nf);
                float4 b1 = *(const float4*)(se + d * LDE + nf + 4);
                float a[8] = {a0.x, a0.y, a0.z, a0.w, a1.x, a1.y, a1.z, a1.w};
                float b[8] = {b0.x, b0.y, b0.z, b0.w, b1.x, b1.y, b1.z, b1.w};
                #pragma unroll
                for (int i = 0; i < 8; i++)
                    #pragma unroll
                    for (int j = 0; j < 8; j++) acc[i][j] += a[i] * b[j];
            }
        }
        float es[8];
        #pragma unroll
        for (int j = 0; j < 8; j++) es[j] = esq[kt + nf + j];
        #pragma unroll
        for (int i = 0; i < 8; i++)
            #pragma unroll
            for (int j = 0; j < 8; j++) {
                float s = (xs[i] + es[j]) - 2.0f * acc[i][j];
                if (s < rmin[i]) { rmin[i] = s; ridx[i] = kt + nf + j; }
            }
    }
    __syncthreads();
    float* redm = sx;
    int* redi = (int*)se;
    const int c = (wave & 1) * 8 + ln;
    #pragma unroll
    for (int i = 0; i < 8; i++) {
        int r = (wave >> 1) * 64 + lm * 8 + i;
        redm[r * 16 + c] = rmin[i];
        redi[r * 16 + c] = ridx[i];
    }
    __syncthreads();
    if (t < BM) {
        float bst = redm[t * 16];
        int bi = redi[t * 16];
        #pragma unroll
        for (int c2 = 1; c2 < 16; c2++) {
            float v = redm[t * 16 + c2];
            int id = redi[t * 16 + c2];
            if (v < bst || (v == bst && id < bi)) { bst = v; bi = id; }
        }
        pmin[(size_t)(row0 + t) * KSPLIT + blockIdx.y] = bst;
        pidx[(size_t)(row0 + t) * KSPLIT + blockIdx.y] = bi;
    }
}

__global__ void vq_final(const float* __restrict__ E, const float* __restrict__ pmin,
                         const int* __restrict__ pidx, float* __restrict__ out_q,
                         float* __restrict__ out_idx) {
    int row = blockIdx.x;
    int lane = threadIdx.x;
    float bst = pmin[(size_t)row * KSPLIT];
    int bi = pidx[(size_t)row * KSPLIT];
    #pragma unroll
    for (int s = 1; s < KSPLIT; s++) {
        float v = pmin[(size_t)row * KSPLIT + s];
        int id = pidx[(size_t)row * KSPLIT + s];
        if (v < bst || (v == bst && id < bi)) { bst = v; bi = id; }
    }
    if (lane == 0) out_idx[row] = (float)bi;
    float4 v = ((const float4*)(E + (size_t)bi * D))[lane];
    ((float4*)(out_q + (size_t)row * D))[lane] = v;
}

// =======================================================================
extern "C" void kernel_launch(void* const* d_in, const int* in_sizes, int n_in,
                              void* d_out, int out_size, void* d_ws, size_t ws_size,
                              hipStream_t stream) {
    const float* X = (const float*)d_in[0];  // [N, D]
    const float* E = (const float*)d_in[1];  // [K, D]
    float* out_q = (float*)d_out;
    float* out_idx = (float*)d_out + (size_t)N * D;

    // fast-path ws: Xh(8M) Eh(4M) esq(32K) pcand(N*CS*16 = 4M) ~= 16.3MB
    const size_t need = (size_t)12 * 1024 * 1024 + 32768 + (size_t)N * CS * 16;
    if (ws_size >= need) {
        _Float16* Xh = (_Float16*)d_ws;
        _Float16* Eh = Xh + (size_t)N * D;
        float* esq = (float*)(Eh + (size_t)K * D);
        float4* pcand = (float4*)(esq + K);

        vq_rowsq<<<K, 64, 0, stream>>>(E, esq);
        vq_prep<<<(N + K) * 32 / 256, 256, 0, stream>>>(X, E, Xh, Eh);
        dim3 grid(CS, N / 128);
        vq_mfma<<<grid, 128, 0, stream>>>(Xh, Eh, esq, pcand);
        vq_rescore<<<N / 4, 256, 0, stream>>>(X, E, pcand, out_q, out_idx);
    } else {
        float* esq = (float*)d_ws;
        float* xsq = esq + K;
        float* pmin = xsq + N;
        int* pidx = (int*)(pmin + (size_t)N * KSPLIT);
        vq_rowsq<<<K, 64, 0, stream>>>(E, esq);
        vq_rowsq<<<N, 64, 0, stream>>>(X, xsq);
        dim3 grid(N / BM, KSPLIT);
        vq_main<<<grid, 256, 0, stream>>>(X, E, xsq, esq, pmin, pidx);
        vq_final<<<N, 64, 0, stream>>>(E, pmin, pidx, out_q, out_idx);
    }
}